// Round 2
// baseline (1214.164 us; speedup 1.0000x reference)
//
#include <hip/hip_runtime.h>
#include <math.h>

#define TBL   (1u << 19)
#define TMASK (TBL - 1u)
#define PRIME1 2654435761u
#define PRIME2 805459861u

struct LevelParams {
    float    scale[16];
    unsigned res[16];
    unsigned dense[16];
};

// No LDS, low VGPR: target 8 waves/SIMD (32 waves/CU, 8 blocks/CU).
__global__ __launch_bounds__(256, 8) void hashgrid_enc(
    const float* __restrict__ coords,
    const float* __restrict__ table,
    float2* __restrict__ out2,   // out viewed as [N][16] float2
    LevelParams lp, unsigned n)
{
    const unsigned t = threadIdx.x;
    const unsigned p = blockIdx.x * 256u + t;
    if (p >= n) return;

    const float x = coords[3ull * p + 0];
    const float y = coords[3ull * p + 1];
    const float z = coords[3ull * p + 2];

    float2* __restrict__ po = out2 + (size_t)p * 16u;

    #pragma unroll 2
    for (int l = 0; l < 16; ++l) {
        const float    s   = lp.scale[l];
        const unsigned res = lp.res[l];
        const float2* __restrict__ tab = (const float2*)table + (size_t)l * TBL;

        // pos = x*scale + 0.5 with no FMA contraction (match numpy exactly)
        float px = __fadd_rn(__fmul_rn(x, s), 0.5f);
        float py = __fadd_rn(__fmul_rn(y, s), 0.5f);
        float pz = __fadd_rn(__fmul_rn(z, s), 0.5f);
        float fx = floorf(px), fy = floorf(py), fz = floorf(pz);
        float wx = px - fx,    wy = py - fy,    wz = pz - fz;
        unsigned gx = (unsigned)fx, gy = (unsigned)fy, gz = (unsigned)fz;

        unsigned idx[8];
        if (lp.dense[l]) {
            const unsigned rm1 = res - 1u;
            unsigned cx0 = min(gx, rm1),      cx1 = min(gx + 1u, rm1);
            unsigned cy0 = min(gy, rm1),      cy1 = min(gy + 1u, rm1);
            unsigned cz0 = min(gz, rm1),      cz1 = min(gz + 1u, rm1);
            unsigned y0 = cy0 * res,          y1 = cy1 * res;
            unsigned z0 = cz0 * res * res,    z1 = cz1 * res * res;
            // corner k: ox=(k>>2)&1, oy=(k>>1)&1, oz=k&1 (meshgrid 'ij')
            idx[0] = cx0 + y0 + z0;
            idx[1] = cx0 + y0 + z1;
            idx[2] = cx0 + y1 + z0;
            idx[3] = cx0 + y1 + z1;
            idx[4] = cx1 + y0 + z0;
            idx[5] = cx1 + y0 + z1;
            idx[6] = cx1 + y1 + z0;
            idx[7] = cx1 + y1 + z1;
        } else {
            unsigned hx0 = gx,          hx1 = gx + 1u;
            unsigned hy0 = gy * PRIME1, hy1 = hy0 + PRIME1;
            unsigned hz0 = gz * PRIME2, hz1 = hz0 + PRIME2;
            idx[0] = (hx0 ^ hy0 ^ hz0) & TMASK;
            idx[1] = (hx0 ^ hy0 ^ hz1) & TMASK;
            idx[2] = (hx0 ^ hy1 ^ hz0) & TMASK;
            idx[3] = (hx0 ^ hy1 ^ hz1) & TMASK;
            idx[4] = (hx1 ^ hy0 ^ hz0) & TMASK;
            idx[5] = (hx1 ^ hy0 ^ hz1) & TMASK;
            idx[6] = (hx1 ^ hy1 ^ hz0) & TMASK;
            idx[7] = (hx1 ^ hy1 ^ hz1) & TMASK;
        }

        float2 v[8];
        #pragma unroll
        for (int k = 0; k < 8; ++k) v[k] = tab[idx[k]];

        float wx0 = 1.f - wx, wy0 = 1.f - wy, wz0 = 1.f - wz;
        float wyz00 = wy0 * wz0, wyz01 = wy0 * wz;
        float wyz10 = wy  * wz0, wyz11 = wy  * wz;
        float cw[8] = { wx0 * wyz00, wx0 * wyz01, wx0 * wyz10, wx0 * wyz11,
                        wx  * wyz00, wx  * wyz01, wx  * wyz10, wx  * wyz11 };

        float f0 = 0.f, f1 = 0.f;
        #pragma unroll
        for (int k = 0; k < 8; ++k) {
            f0 = fmaf(cw[k], v[k].x, f0);
            f1 = fmaf(cw[k], v[k].y, f1);
        }

        po[l] = make_float2(f0, f1);
    }
}

extern "C" void kernel_launch(void* const* d_in, const int* in_sizes, int n_in,
                              void* d_out, int out_size, void* d_ws, size_t ws_size,
                              hipStream_t stream) {
    (void)n_in; (void)out_size; (void)d_ws; (void)ws_size;
    const float* coords = (const float*)d_in[0];
    const float* table  = (const float*)d_in[1];
    float2* out2 = (float2*)d_out;

    LevelParams lp;
    for (int l = 0; l < 16; ++l) {
        double scale = 16.0 * pow(1.4472692012786865, (double)l) - 1.0;
        int res = (int)ceil(scale) + 1;
        lp.scale[l] = (float)scale;
        lp.res[l]   = (unsigned)res;
        long long r3 = (long long)res * res * res;
        lp.dense[l] = (r3 <= (long long)TBL) ? 1u : 0u;
    }

    unsigned n = (unsigned)(in_sizes[0] / 3);
    unsigned blocks = (n + 255u) / 256u;
    hipLaunchKernelGGL(hashgrid_enc, dim3(blocks), dim3(256), 0, stream,
                       coords, table, out2, lp, n);
}

// Round 3
// 719.278 us; speedup vs baseline: 1.6880x; 1.6880x over previous
//
#include <hip/hip_runtime.h>
#include <math.h>

#define TBL   (1u << 19)
#define TMASK (TBL - 1u)
#define PRIME1 2654435761u
#define PRIME2 805459861u

typedef float v2f __attribute__((ext_vector_type(2)));

struct LevelParams {
    float    scale[16];
    unsigned res[16];
    unsigned dense[16];
};

__device__ __forceinline__ void corner_indices(
    float x, float y, float z, float s, unsigned res, unsigned dense,
    unsigned idx[8], float* wx, float* wy, float* wz)
{
    float px = __fadd_rn(__fmul_rn(x, s), 0.5f);
    float py = __fadd_rn(__fmul_rn(y, s), 0.5f);
    float pz = __fadd_rn(__fmul_rn(z, s), 0.5f);
    float fx = floorf(px), fy = floorf(py), fz = floorf(pz);
    *wx = px - fx; *wy = py - fy; *wz = pz - fz;
    unsigned gx = (unsigned)fx, gy = (unsigned)fy, gz = (unsigned)fz;

    if (dense) {
        const unsigned rm1 = res - 1u;
        unsigned cx0 = min(gx, rm1),   cx1 = min(gx + 1u, rm1);
        unsigned cy0 = min(gy, rm1),   cy1 = min(gy + 1u, rm1);
        unsigned cz0 = min(gz, rm1),   cz1 = min(gz + 1u, rm1);
        unsigned y0 = cy0 * res,       y1 = cy1 * res;
        unsigned z0 = cz0 * res * res, z1 = cz1 * res * res;
        idx[0] = cx0 + y0 + z0;  idx[1] = cx0 + y0 + z1;
        idx[2] = cx0 + y1 + z0;  idx[3] = cx0 + y1 + z1;
        idx[4] = cx1 + y0 + z0;  idx[5] = cx1 + y0 + z1;
        idx[6] = cx1 + y1 + z0;  idx[7] = cx1 + y1 + z1;
    } else {
        unsigned hx0 = gx,          hx1 = gx + 1u;
        unsigned hy0 = gy * PRIME1, hy1 = hy0 + PRIME1;
        unsigned hz0 = gz * PRIME2, hz1 = hz0 + PRIME2;
        idx[0] = (hx0 ^ hy0 ^ hz0) & TMASK;
        idx[1] = (hx0 ^ hy0 ^ hz1) & TMASK;
        idx[2] = (hx0 ^ hy1 ^ hz0) & TMASK;
        idx[3] = (hx0 ^ hy1 ^ hz1) & TMASK;
        idx[4] = (hx1 ^ hy0 ^ hz0) & TMASK;
        idx[5] = (hx1 ^ hy0 ^ hz1) & TMASK;
        idx[6] = (hx1 ^ hy1 ^ hz0) & TMASK;
        idx[7] = (hx1 ^ hy1 ^ hz1) & TMASK;
    }
}

__device__ __forceinline__ v2f interp_level(
    const float2* __restrict__ tab,
    float x, float y, float z, float s, unsigned res, unsigned dense)
{
    unsigned idx[8];
    float wx, wy, wz;
    corner_indices(x, y, z, s, res, dense, idx, &wx, &wy, &wz);

    float2 v[8];
    #pragma unroll
    for (int k = 0; k < 8; ++k) v[k] = tab[idx[k]];

    float wx0 = 1.f - wx, wy0 = 1.f - wy, wz0 = 1.f - wz;
    float wyz00 = wy0 * wz0, wyz01 = wy0 * wz;
    float wyz10 = wy  * wz0, wyz11 = wy  * wz;
    float cw[8] = { wx0 * wyz00, wx0 * wyz01, wx0 * wyz10, wx0 * wyz11,
                    wx  * wyz00, wx  * wyz01, wx  * wyz10, wx  * wyz11 };

    float f0 = 0.f, f1 = 0.f;
    #pragma unroll
    for (int k = 0; k < 8; ++k) {
        f0 = fmaf(cw[k], v[k].x, f0);
        f1 = fmaf(cw[k], v[k].y, f1);
    }
    v2f r; r.x = f0; r.y = f1;
    return r;
}

// ---------- Pass A: level-major compute, coalesced nt-stores into ws ----------
__global__ __launch_bounds__(256, 8) void pass_a(
    const float* __restrict__ coords,
    const float* __restrict__ table,
    v2f* __restrict__ ws,            // [16][N] float2, level-major
    LevelParams lp, unsigned n)
{
    const unsigned l = blockIdx.y;
    const unsigned p = blockIdx.x * 256u + threadIdx.x;
    if (p >= n) return;

    const float x = coords[3ull * p + 0];
    const float y = coords[3ull * p + 1];
    const float z = coords[3ull * p + 2];

    const float2* __restrict__ tab = (const float2*)table + (size_t)l * TBL;
    v2f r = interp_level(tab, x, y, z, lp.scale[l], lp.res[l], lp.dense[l]);
    __builtin_nontemporal_store(r, ws + (size_t)l * n + p);
}

// ---------- Pass B: ws[16][N][2] -> out[N][32] transpose, streaming ----------
__global__ __launch_bounds__(256, 4) void pass_b(
    const v2f* __restrict__ ws,
    float* __restrict__ out, unsigned n)
{
    __shared__ float lds[256 * 33];
    const unsigned t  = threadIdx.x;
    const unsigned p0 = blockIdx.x * 256u;
    const unsigned p  = p0 + t;

    #pragma unroll
    for (int l = 0; l < 16; ++l) {
        v2f v = {0.f, 0.f};
        if (p < n) v = __builtin_nontemporal_load(ws + (size_t)l * n + p);
        lds[t * 33u + 2u * l]      = v.x;
        lds[t * 33u + 2u * l + 1u] = v.y;
    }
    __syncthreads();

    const size_t base  = (size_t)p0 * 32u;
    const size_t total = (size_t)n * 32u;
    #pragma unroll
    for (int i = 0; i < 32; ++i) {
        size_t j = (size_t)i * 256u + t;
        size_t o = base + j;
        if (o < total)
            __builtin_nontemporal_store(
                lds[(unsigned)(j >> 5) * 33u + ((unsigned)j & 31u)], out + o);
    }
}

// ---------- Fallback: R1 single-kernel (if ws too small) ----------
__global__ __launch_bounds__(256, 4) void hashgrid_enc(
    const float* __restrict__ coords,
    const float* __restrict__ table,
    float* __restrict__ out,
    LevelParams lp, unsigned n)
{
    __shared__ float lds[256 * 33];
    const unsigned t = threadIdx.x;
    const unsigned p = blockIdx.x * 256u + t;

    float x = 0.f, y = 0.f, z = 0.f;
    if (p < n) {
        x = coords[3ull * p + 0];
        y = coords[3ull * p + 1];
        z = coords[3ull * p + 2];
    }

    #pragma unroll 2
    for (int l = 0; l < 16; ++l) {
        const float2* __restrict__ tab = (const float2*)table + (size_t)l * TBL;
        v2f r = interp_level(tab, x, y, z, lp.scale[l], lp.res[l], lp.dense[l]);
        lds[t * 33u + 2u * l]      = r.x;
        lds[t * 33u + 2u * l + 1u] = r.y;
    }
    __syncthreads();

    const size_t base  = (size_t)blockIdx.x * 8192u;
    const size_t total = (size_t)n * 32u;
    #pragma unroll
    for (int i = 0; i < 32; ++i) {
        size_t j = (size_t)i * 256u + t;
        size_t o = base + j;
        if (o < total)
            out[o] = lds[(unsigned)(j >> 5) * 33u + ((unsigned)j & 31u)];
    }
}

extern "C" void kernel_launch(void* const* d_in, const int* in_sizes, int n_in,
                              void* d_out, int out_size, void* d_ws, size_t ws_size,
                              hipStream_t stream) {
    (void)n_in; (void)out_size;
    const float* coords = (const float*)d_in[0];
    const float* table  = (const float*)d_in[1];
    float* out = (float*)d_out;

    LevelParams lp;
    for (int l = 0; l < 16; ++l) {
        double scale = 16.0 * pow(1.4472692012786865, (double)l) - 1.0;
        int res = (int)ceil(scale) + 1;
        lp.scale[l] = (float)scale;
        lp.res[l]   = (unsigned)res;
        long long r3 = (long long)res * res * res;
        lp.dense[l] = (r3 <= (long long)TBL) ? 1u : 0u;
    }

    unsigned n = (unsigned)(in_sizes[0] / 3);
    unsigned chunks = (n + 255u) / 256u;
    size_t ws_needed = (size_t)16 * n * sizeof(v2f);

    if (ws_size >= ws_needed) {
        v2f* ws = (v2f*)d_ws;
        hipLaunchKernelGGL(pass_a, dim3(chunks, 16), dim3(256), 0, stream,
                           coords, table, ws, lp, n);
        hipLaunchKernelGGL(pass_b, dim3(chunks), dim3(256), 0, stream,
                           ws, out, n);
    } else {
        hipLaunchKernelGGL(hashgrid_enc, dim3(chunks), dim3(256), 0, stream,
                           coords, table, out, lp, n);
    }
}